// Round 4
// baseline (55.239 us; speedup 1.0000x reference)
//
#include <hip/hip_runtime.h>
#include <math.h>

#define K_SIZE 5
#define EPS    1e-6f
#define EPS_L  1e-3f
#define EPS_W  1e-3f

#define BATCH 4
#define HGT   512
#define WID   512
#define HW    (HGT * WID)

typedef int int32x4 __attribute__((ext_vector_type(4)));

// Raw buffer load with hardware bounds check: OOB -> returns 0.0f
__device__ float llvm_amdgcn_raw_buffer_load_fp32(int32x4 srsrc, int voffset,
                                                  int soffset, int aux)
    __asm("llvm.amdgcn.raw.buffer.load.f32");

__global__ __launch_bounds__(256) void fused_sample_kernel(
    const float* __restrict__ input,   // (B,1,H,W)
    const float* __restrict__ Lp,      // (B,H,W,3)
    const float* __restrict__ wbuf,    // (B,2,H,W)
    float* __restrict__ out)           // (B,1,H,W)
{
#pragma clang fp contract(off)
    const int idx = blockIdx.x * blockDim.x + threadIdx.x;

    const int b = blockIdx.x >> 10;     // 1024 blocks per image (uniform per block)
    const int p = idx & (HW - 1);
    const int y = p >> 9;
    const int x = p & (WID - 1);

    // SRD for this batch's image: base, stride=0, num_records = HW*4 bytes,
    // word3 = 0x00020000 (raw untyped dword). OOB loads return 0.
    union {
        struct { const void* base; unsigned num; unsigned cfg; } s;
        int32x4 v;
    } desc;
    desc.s.base = (const void*)(input + (size_t)b * HW);
    desc.s.num  = HW * 4u;
    desc.s.cfg  = 0x00020000u;
    const int32x4 rsrc = desc.v;

    // ---- per-pixel matrix (exactly mirrors numpy op order; amplified path) ----
    const size_t l_off = (size_t)idx * 3;
    const float L0 = Lp[l_off + 0];
    const float L1 = Lp[l_off + 1];
    const float L2 = Lp[l_off + 2];

    const float a  = fabsf(L0) + EPS_L;
    const float bb = L1;
    const float c  = fabsf(L2) + EPS_L;

    const float M00 = a * a;
    const float M01 = a * bb;
    const float M11 = (bb * bb) + (c * c);

    const float d00 = M00 + EPS;
    const float d11 = M11 + EPS;
    const float det = (d00 * d11) - (M01 * M01);
    const float I00 = d11 / det;          // IEEE f32 div, same as np
    const float I01 = (-M01) / det;
    const float I11 = d00 / det;

    const float wx = wbuf[(size_t)b * 2 * HW + p];
    const float wy = wbuf[(size_t)b * 2 * HW + HW + p];

    const float q    = (((I00 * wx) * wx) + (((2.0f * I01) * wx) * wy)) + ((I11 * wy) * wy);
    const float norm = sqrtf(q + EPS);

    const float e    = (float)exp((double)(-norm));   // correctly-rounded f32 exp
    const float sig  = 1.0f / (1.0f + e);
    const float tuned = ((sig - 0.5f) * 2.0f) * (1.0f - EPS_W);
    const float scale = tuned / (norm + EPS);         // IEEE div
    const float wtx = wx * scale;
    const float wty = wy * scale;

    // cos/sin of the FLOAT32-ROUNDED theta_k
    const float CT[K_SIZE] = { 1.0f,  0.30901696090f, -0.80901703575f, -0.80901693229f,  0.30901712828f };
    const float ST[K_SIZE] = { 0.0f,  0.95105652717f,  0.58778519534f, -0.58778533774f, -0.95105647279f };
    const float SV[K_SIZE] = { 0.2f, 0.4f, 0.6f, 0.8f, 1.0f };

    const float fy = (float)y;
    const float fx = (float)x;

    float acc0 = 0.0f;
    float acc1 = 0.0f;

    #pragma unroll
    for (int k = 0; k < K_SIZE; ++k) {
        const float ct = CT[k];
        const float st = ST[k];
        // amplified path: keep exact left-assoc, no contraction
        const float quad = (((M00 * ct) * ct) + (((2.0f * M01) * ct) * st)) + ((M11 * st) * st);
        const float F    = (sqrtf(quad) + (wtx * ct)) + (wty * st);
        const float Fe   = F + EPS;
        // downstream of cancellation: approx rcp safe (position error ~1e-7 rel)
        const float rFe  = __builtin_amdgcn_rcpf(Fe);
        const float yx   = ct * rFe;
        const float yy   = st * rFe;

        #pragma unroll
        for (int s = 0; s < K_SIZE; ++s) {
            const float sv = SV[s];
            const float gy = fmaf(sv, yy, fy);
            const float gx = fmaf(sv, yx, fx);

            const int   y0i = (int)floorf(gy);      // v_cvt_flr_i32_f32 (saturating)
            const int   x0i = (int)floorf(gx);
            const float wyf = __builtin_amdgcn_fractf(gy);
            const float wxf = __builtin_amdgcn_fractf(gx);

            // y handled by HW bounds check: OOB row -> address outside SRD -> 0.
            // (|gy| <= ~1e6 so (unsigned)y0i<<11 never wraps back below 1MB.)
            const unsigned r0 = (unsigned)y0i << 11;          // byte offset of row y0
            const unsigned r1 = r0 + (WID * 4u);              // row y0+1

            // x must be clamped (x wrap would alias a neighboring row)
            const int x1i = x0i + 1;
            const bool vx0 = (unsigned)x0i < (unsigned)WID;
            const bool vx1 = (unsigned)x1i < (unsigned)WID;
            const unsigned x0v = (unsigned)min(max(x0i, 0), WID - 1) << 2;
            const unsigned x1v = (unsigned)min(max(x1i, 0), WID - 1) << 2;

            const float v00 = llvm_amdgcn_raw_buffer_load_fp32(rsrc, (int)(r0 + x0v), 0, 0);
            const float v01 = llvm_amdgcn_raw_buffer_load_fp32(rsrc, (int)(r0 + x1v), 0, 0);
            const float v10 = llvm_amdgcn_raw_buffer_load_fp32(rsrc, (int)(r1 + x0v), 0, 0);
            const float v11 = llvm_amdgcn_raw_buffer_load_fp32(rsrc, (int)(r1 + x1v), 0, 0);

            const float zx0 = vx0 ? (1.0f - wxf) : 0.0f;
            const float zx1 = vx1 ? wxf : 0.0f;

            const float row0 = fmaf(v01, zx1, v00 * zx0);
            const float row1 = fmaf(v11, zx1, v10 * zx0);

            if (s & 1) {
                acc1 = fmaf(1.0f - wyf, row0, acc1);
                acc1 = fmaf(wyf,        row1, acc1);
            } else {
                acc0 = fmaf(1.0f - wyf, row0, acc0);
                acc0 = fmaf(wyf,        row1, acc0);
            }
        }
    }

    out[idx] = (acc0 + acc1) / (float)(K_SIZE * K_SIZE);
}

extern "C" void kernel_launch(void* const* d_in, const int* in_sizes, int n_in,
                              void* d_out, int out_size, void* d_ws, size_t ws_size,
                              hipStream_t stream) {
    const float* input = (const float*)d_in[0];
    const float* Lp    = (const float*)d_in[1];
    const float* wbuf  = (const float*)d_in[2];
    float* out = (float*)d_out;

    const int total = BATCH * HW;            // 1,048,576
    const int block = 256;
    const int grid  = (total + block - 1) / block;   // 4096
    fused_sample_kernel<<<grid, block, 0, stream>>>(input, Lp, wbuf, out);
}